// Round 10
// baseline (115.956 us; speedup 1.0000x reference)
//
#include <hip/hip_runtime.h>

#define E_DIM 64
#define N_E   1024
#define N_PTS 32768

// d_out layout (floats):
#define OFF_ZQ   1
#define OFF_PERP 2097153
#define OFF_OH   2097154
#define OFF_IDX  35651586

// d_ws layout (bytes):
#define WS_LOSS    0        // float
#define WS_FIXCNT  4        // uint
#define WS_COUNTS  256      // uint[1024]
#define WS_NORMS   8192     // float[1024]
#define WS_IDX     16384    // int[32768]        (ends 147456)
#define WS_FIXLIST 147456   // int[8192]         (ends 180224)
#define WS_NZ      180224   // float[32768]      (ends 311296)
#define WS_EBHL    311296   // ushort[1024*128]  hi[64],lo[64] per code
#define FIXCAP     8192

typedef __attribute__((ext_vector_type(8))) short short8;
typedef __attribute__((ext_vector_type(4))) float f32x4;
typedef __attribute__((ext_vector_type(4))) unsigned int u32x4;

// numpy pairwise_sum replication for n=64 over squares (fp32, no contraction)
__device__ __forceinline__ float np_sum64_sq(const float* a) {
#pragma clang fp contract(off)
    float r0 = a[0] * a[0];
    float r1 = a[1] * a[1];
    float r2 = a[2] * a[2];
    float r3 = a[3] * a[3];
    float r4 = a[4] * a[4];
    float r5 = a[5] * a[5];
    float r6 = a[6] * a[6];
    float r7 = a[7] * a[7];
#pragma unroll
    for (int m = 1; m < 8; ++m) {
        r0 += a[8 * m + 0] * a[8 * m + 0];
        r1 += a[8 * m + 1] * a[8 * m + 1];
        r2 += a[8 * m + 2] * a[8 * m + 2];
        r3 += a[8 * m + 3] * a[8 * m + 3];
        r4 += a[8 * m + 4] * a[8 * m + 4];
        r5 += a[8 * m + 5] * a[8 * m + 5];
        r6 += a[8 * m + 6] * a[8 * m + 6];
        r7 += a[8 * m + 7] * a[8 * m + 7];
    }
    return ((r0 + r1) + (r2 + r3)) + ((r4 + r5) + (r6 + r7));
}

__device__ __forceinline__ unsigned short rn_bf16(float f) {
    unsigned int u = __float_as_uint(f);
    return (unsigned short)((u + 0x7FFFu + ((u >> 16) & 1u)) >> 16);
}
__device__ __forceinline__ float bf16_to_f(unsigned short h) {
    return __uint_as_float(((unsigned int)h) << 16);
}

// prep: codebook -> hi/lo bf16 + ||e||^2; block 0 also zeroes ws accumulators
__global__ void eprep_kernel(const float* __restrict__ emb,
                             unsigned short* __restrict__ ebhl,
                             float* __restrict__ norms,
                             unsigned int* __restrict__ ws_head,
                             unsigned int* __restrict__ counts) {
    int k = blockIdx.x * blockDim.x + threadIdx.x;
    if (blockIdx.x == 0) {
        if (threadIdx.x < 2) ws_head[threadIdx.x] = 0u;
        *reinterpret_cast<uint4*>(&counts[threadIdx.x * 4]) = make_uint4(0u, 0u, 0u, 0u);
    }
    if (k >= N_E) return;
    float er[E_DIM];
    const float4* e4 = reinterpret_cast<const float4*>(emb) + (size_t)k * (E_DIM / 4);
#pragma unroll
    for (int i = 0; i < E_DIM / 4; ++i)
        *reinterpret_cast<float4*>(&er[i * 4]) = e4[i];
    norms[k] = np_sum64_sq(er);
    unsigned int* rh = (unsigned int*)(ebhl + (size_t)k * 128);
    unsigned int* rl = rh + 32;
#pragma unroll
    for (int c = 0; c < E_DIM; c += 2) {
        unsigned short h0 = rn_bf16(er[c]);
        unsigned short h1 = rn_bf16(er[c + 1]);
        unsigned short l0 = rn_bf16(er[c] - bf16_to_f(h0));
        unsigned short l1 = rn_bf16(er[c + 1] - bf16_to_f(h1));
        rh[c / 2] = (unsigned int)h0 | ((unsigned int)h1 << 16);
        rl[c / 2] = (unsigned int)l0 | ((unsigned int)l1 << 16);
    }
}

// ---------------- kargmin: 1024 blocks x 128 thr (2 waves) ----------------
// Block = 32 points; each wave owns 16 points x ALL 1024 codes (no cross-
// wave merge). Codebook streamed in 32-code chunks through padded LDS
// (ROWPAD keeps consecutive-8-lane quad disjointness) with a 2-deep reg
// pipeline; barriers sync only 2 waves.
#define KCHUNK 32
#define ROWPAD 136   // ushorts per padded code row (128 + 8)

#define GLD(reg, ch) {                                                        \
        const u32x4* gp = reinterpret_cast<const u32x4*>(ebhl) + (ch) * 512;  \
        _Pragma("unroll")                                                     \
        for (int i = 0; i < 4; ++i) reg[i] = gp[tid + i * 128];               \
    }
#define SWR(bufp, reg) {                                                      \
        _Pragma("unroll")                                                     \
        for (int i = 0; i < 4; ++i) {                                         \
            int gci = tid + i * 128;                                          \
            int code = gci >> 4, cb = gci & 15;                               \
            *reinterpret_cast<u32x4*>(&(bufp)[code * ROWPAD + cb * 8]) = reg[i];\
        }                                                                     \
    }
#define COMPT2(bufp, ch) {                                                    \
        _Pragma("unroll")                                                     \
        for (int t = 0; t < 2; ++t) {                                         \
            const unsigned short* rb = &(bufp)[(t * 16 + lc) * ROWPAD];       \
            short8 eh0 = *reinterpret_cast<const short8*>(rb + rg * 8);       \
            short8 eh1 = *reinterpret_cast<const short8*>(rb + 32 + rg * 8);  \
            short8 el0 = *reinterpret_cast<const short8*>(rb + 64 + rg * 8);  \
            short8 el1 = *reinterpret_cast<const short8*>(rb + 96 + rg * 8);  \
            f32x4 pA = {0.f, 0.f, 0.f, 0.f};                                  \
            f32x4 pB = {0.f, 0.f, 0.f, 0.f};                                  \
            pA = __builtin_amdgcn_mfma_f32_16x16x32_bf16(zh0, eh0, pA, 0, 0, 0);\
            pA = __builtin_amdgcn_mfma_f32_16x16x32_bf16(zh1, eh1, pA, 0, 0, 0);\
            pB = __builtin_amdgcn_mfma_f32_16x16x32_bf16(zh0, el0, pB, 0, 0, 0);\
            pB = __builtin_amdgcn_mfma_f32_16x16x32_bf16(zh1, el1, pB, 0, 0, 0);\
            pB = __builtin_amdgcn_mfma_f32_16x16x32_bf16(zl0, eh0, pB, 0, 0, 0);\
            pB = __builtin_amdgcn_mfma_f32_16x16x32_bf16(zl1, eh1, pB, 0, 0, 0);\
            const int code = (ch) * KCHUNK + t * 16 + lc;                     \
            const float ne_c = sne[code];                                     \
            _Pragma("unroll")                                                 \
            for (int r = 0; r < 4; ++r) {                                     \
                float t1 = nzr[r] + ne_c;                                     \
                float d = fmaf(-2.0f, pA[r] + pB[r], t1);                     \
                float m = fminf(d, b2[r]);                                    \
                bool lt = d < b1[r];                                          \
                b2[r] = lt ? b1[r] : m;                                       \
                k1[r] = lt ? code : k1[r];                                    \
                b1[r] = fminf(d, b1[r]);                                      \
            }                                                                 \
        }                                                                     \
    }

__global__ __launch_bounds__(128) void kargmin_kernel(
    const float* __restrict__ z, const unsigned short* __restrict__ ebhl,
    const float* __restrict__ norms,
    int* __restrict__ idx, unsigned int* __restrict__ counts,
    float* __restrict__ out_idx, float* __restrict__ nzG,
    unsigned int* __restrict__ fixcnt, int* __restrict__ fixlist)
{
    __shared__ float szt[32][68];                   // 8704 B
    __shared__ float snz[32];                       // 128 B
    __shared__ float sne[N_E];                      // 4096 B
    __shared__ unsigned short sbuf[2][KCHUNK * ROWPAD]; // 2 x 8704 B

    const int tid = threadIdx.x;
    const int wave = tid >> 6;
    const int lane = tid & 63;
    const int lc = lane & 15;
    const int rg = lane >> 4;
    const int pbase = blockIdx.x * 32;
    const int b = pbase >> 10;
    const int hw0 = pbase & 1023;

    // stage z tile: 32 consecutive pts per c -> 128B coalesced
    {
        const int pt = tid & 31, c0 = tid >> 5;   // c0 = 0..3
#pragma unroll
        for (int cg = 0; cg < 16; ++cg) {
            int c = cg * 4 + c0;
            szt[pt][c] = z[((b * E_DIM + c) << 10) + hw0 + pt];
        }
    }
#pragma unroll
    for (int i = 0; i < 2; ++i)
        *reinterpret_cast<float4*>(&sne[(tid + i * 128) * 4]) =
            *reinterpret_cast<const float4*>(norms + (tid + i * 128) * 4);
    __syncthreads();
    if (tid < 32) {
        float v = np_sum64_sq(&szt[tid][0]);
        snz[tid] = v;
        nzG[pbase + tid] = v;
    }
    __syncthreads();

    // A-fragments: wave's point pa = wave*16+lc, K-chunks per rg
    const int pa = wave * 16 + lc;
    float4 zv0 = *reinterpret_cast<const float4*>(&szt[pa][rg * 8]);
    float4 zv1 = *reinterpret_cast<const float4*>(&szt[pa][rg * 8 + 4]);
    float4 zv2 = *reinterpret_cast<const float4*>(&szt[pa][32 + rg * 8]);
    float4 zv3 = *reinterpret_cast<const float4*>(&szt[pa][32 + rg * 8 + 4]);
    float zt0[8] = {zv0.x, zv0.y, zv0.z, zv0.w, zv1.x, zv1.y, zv1.z, zv1.w};
    float zt1[8] = {zv2.x, zv2.y, zv2.z, zv2.w, zv3.x, zv3.y, zv3.z, zv3.w};
    short8 zh0, zl0, zh1, zl1;
#pragma unroll
    for (int j = 0; j < 8; ++j) {
        unsigned short h0 = rn_bf16(zt0[j]);
        zh0[j] = (short)h0;
        zl0[j] = (short)rn_bf16(zt0[j] - bf16_to_f(h0));
        unsigned short h1 = rn_bf16(zt1[j]);
        zh1[j] = (short)h1;
        zl1[j] = (short)rn_bf16(zt1[j] - bf16_to_f(h1));
    }

    float nzr[4];
#pragma unroll
    for (int r = 0; r < 4; ++r) nzr[r] = snz[wave * 16 + rg * 4 + r];

    float b1[4] = {3.4028235e38f, 3.4028235e38f, 3.4028235e38f, 3.4028235e38f};
    float b2[4] = {3.4028235e38f, 3.4028235e38f, 3.4028235e38f, 3.4028235e38f};
    int k1[4] = {0, 0, 0, 0};

    u32x4 rA[4], rB[4];
    GLD(rA, 0);
    SWR(sbuf[0], rA);
    GLD(rB, 1);
    __syncthreads();

    for (int it = 0; it < 16; ++it) {
        const int ch0 = 2 * it, ch1 = 2 * it + 1;
        COMPT2(sbuf[0], ch0);
        SWR(sbuf[1], rB);
        if (it < 15) GLD(rA, ch0 + 2);
        __syncthreads();
        COMPT2(sbuf[1], ch1);
        if (it < 15) {
            SWR(sbuf[0], rA);
            GLD(rB, ch1 + 2);
        }
        __syncthreads();
    }

    // intra-wave top-2 merge across the 16 code-column lanes
#pragma unroll
    for (int off = 1; off < 16; off <<= 1) {
#pragma unroll
        for (int r = 0; r < 4; ++r) {
            float ob1 = __shfl_xor(b1[r], off, 64);
            float ob2 = __shfl_xor(b2[r], off, 64);
            int   ok1 = __shfl_xor(k1[r], off, 64);
            float nb2 = fminf(fmaxf(b1[r], ob1), fminf(b2[r], ob2));
            if (ob1 < b1[r] || (ob1 == b1[r] && ok1 < k1[r])) { b1[r] = ob1; k1[r] = ok1; }
            b2[r] = nb2;
        }
    }

    if (lc == 0) {
#pragma unroll
        for (int r = 0; r < 4; ++r) {
            int p = pbase + wave * 16 + rg * 4 + r;
            idx[p] = k1[r];
            out_idx[p] = (float)k1[r];
            atomicAdd(&counts[k1[r]], 1u);
            float gap = b2[r] - b1[r];
            if (gap < 3e-5f || (b1[r] >= 128.f && gap < 6.5e-5f)) {
                unsigned int slot = atomicAdd(fixcnt, 1u);
                if (slot < FIXCAP) fixlist[slot] = p;
            }
        }
    }
}

// ---------------- kfix: wave-per-flagged-point, coalesced fp64 ----------------
__global__ __launch_bounds__(256) void kfix_kernel(
    const float* __restrict__ z, const float* __restrict__ emb,
    const float* __restrict__ norms, const float* __restrict__ nzG,
    int* __restrict__ idx, unsigned int* __restrict__ counts,
    float* __restrict__ out_idx,
    const unsigned int* __restrict__ fixcnt,
    const int* __restrict__ fixlist)
{
    unsigned int n = *fixcnt;
    if (n > FIXCAP) n = FIXCAP;
    const int lane = threadIdx.x & 63;
    const int kk = lane & 15;     // code-in-batch
    const int cg = lane >> 4;     // c-quarter 0..3
    const unsigned int slot = blockIdx.x * 4 + (threadIdx.x >> 6);

    for (unsigned int it = slot; it < n; it += 4096) {
        const int p = fixlist[it];
        const int b = p >> 10, hw = p & 1023;
        double zc[16];
#pragma unroll
        for (int j = 0; j < 16; ++j)
            zc[j] = (double)z[((b * E_DIM + cg * 16 + j) << 10) + hw];
        const float nz = nzG[p];

        float best = 3.4028235e38f;
        int bestk = 0;
        for (int batch = 0; batch < 64; ++batch) {
            const int k = batch * 16 + kk;
            const float4* er = reinterpret_cast<const float4*>(
                emb + (size_t)k * E_DIM + cg * 16);
            double acc = 0.0;
#pragma unroll
            for (int i = 0; i < 4; ++i) {
                float4 ev = er[i];
                acc += (double)ev.x * zc[i * 4 + 0];
                acc += (double)ev.y * zc[i * 4 + 1];
                acc += (double)ev.z * zc[i * 4 + 2];
                acc += (double)ev.w * zc[i * 4 + 3];
            }
            acc += __shfl_xor(acc, 16, 64);
            acc += __shfl_xor(acc, 32, 64);
            float dotf = (float)acc;
            float d;
            {
#pragma clang fp contract(off)
                float t1 = nz + norms[k];
                d = t1 - 2.0f * dotf;
            }
            if (d < best) { best = d; bestk = k; }
        }
#pragma unroll
        for (int off = 1; off < 16; off <<= 1) {
            float ob = __shfl_xor(best, off, 64);
            int   ok = __shfl_xor(bestk, off, 64);
            if (ob < best || (ob == best && ok < bestk)) { best = ob; bestk = ok; }
        }
        if (lane == 0) {
            int oldk = idx[p];
            if (bestk != oldk) {
                idx[p] = bestk;
                out_idx[p] = (float)bestk;
                atomicSub(&counts[oldk], 1u);
                atomicAdd(&counts[bestk], 1u);
            }
        }
    }
}

// ---------------- kzq: LDS-transpose gather + fused loss + one-hot ones ----
__global__ __launch_bounds__(256) void kzq_kernel(
    const float* __restrict__ z, const float* __restrict__ emb,
    const int* __restrict__ idx,
    float* __restrict__ zq_out, float* __restrict__ oh,
    float* __restrict__ loss_accum)
{
    __shared__ float se[64 * 65];
    __shared__ int sk[64];
    __shared__ float wsum[4];

    const int tid = threadIdx.x;
    const int pbase = blockIdx.x * 64;
    const int b = pbase >> 10;
    const int hw0 = pbase & 1023;

    if (tid < 64) sk[tid] = idx[pbase + tid];
    __syncthreads();

    // one-hot ones (buffer pre-zeroed by the memset node)
    if (tid < 64)
        oh[(size_t)(pbase + tid) * N_E + sk[tid]] = 1.0f;

    // stage rows: 1024 float4s, 4 per thread, contiguous within each row
    const float4* emb4 = reinterpret_cast<const float4*>(emb);
#pragma unroll
    for (int i = 0; i < 4; ++i) {
        int fi = tid + i * 256;
        int row = fi >> 4, c4 = fi & 15;
        float4 v = emb4[(size_t)sk[row] * 16 + c4];
        se[row * 65 + c4 * 4 + 0] = v.x;
        se[row * 65 + c4 * 4 + 1] = v.y;
        se[row * 65 + c4 * 4 + 2] = v.z;
        se[row * 65 + c4 * 4 + 3] = v.w;
    }
    __syncthreads();

    const int p = tid & 63;
    const int cgrp = tid >> 6;
    float ssum = 0.f;
#pragma unroll
    for (int j = 0; j < 16; ++j) {
        const int c = cgrp * 16 + j;
        const int f = ((b * E_DIM + c) << 10) + hw0 + p;
        float q = se[p * 65 + c];
        float zv = z[f];
        __builtin_nontemporal_store(q, &zq_out[f]);
        float dd = q - zv;
        ssum += dd * dd;
    }
#pragma unroll
    for (int off = 32; off > 0; off >>= 1) ssum += __shfl_down(ssum, off, 64);
    const int lane = tid & 63, wid = tid >> 6;
    if (lane == 0) wsum[wid] = ssum;
    __syncthreads();
    if (tid == 0)
        atomicAdd(loss_accum, wsum[0] + wsum[1] + wsum[2] + wsum[3]);
}

__global__ void kfin_kernel(const unsigned int* __restrict__ counts,
                            const float* __restrict__ loss_accum,
                            float* __restrict__ out_loss, float* __restrict__ out_perp)
{
    int k = threadIdx.x;
    float em = (float)counts[k] / (float)N_PTS;
    float v = em * logf(em + 1e-10f);
#pragma unroll
    for (int off = 32; off > 0; off >>= 1) v += __shfl_down(v, off, 64);
    __shared__ float sb[16];
    int lane = k & 63, wid = k >> 6;
    if (lane == 0) sb[wid] = v;
    __syncthreads();
    if (k == 0) {
        float ssum = 0.f;
#pragma unroll
        for (int i = 0; i < 16; ++i) ssum += sb[i];
        *out_perp = expf(-ssum);
        *out_loss = 1.25f * (*loss_accum) / 2097152.f;
    }
}

extern "C" void kernel_launch(void* const* d_in, const int* in_sizes, int n_in,
                              void* d_out, int out_size, void* d_ws, size_t ws_size,
                              hipStream_t stream) {
    const float* z   = (const float*)d_in[0];
    const float* emb = (const float*)d_in[1];
    float* out = (float*)d_out;

    float* out_loss = out;
    float* out_zq   = out + OFF_ZQ;
    float* out_perp = out + OFF_PERP;
    float* out_oh   = out + OFF_OH;
    float* out_idx  = out + OFF_IDX;

    char* ws = (char*)d_ws;
    float*          loss_accum = (float*)(ws + WS_LOSS);
    unsigned int*   ws_head    = (unsigned int*)(ws + WS_LOSS);
    unsigned int*   fixcnt     = (unsigned int*)(ws + WS_FIXCNT);
    unsigned int*   counts     = (unsigned int*)(ws + WS_COUNTS);
    float*          norms      = (float*)(ws + WS_NORMS);
    int*            idx        = (int*)(ws + WS_IDX);
    int*            fixlist    = (int*)(ws + WS_FIXLIST);
    float*          nzG        = (float*)(ws + WS_NZ);
    unsigned short* ebhl       = (unsigned short*)(ws + WS_EBHL);

    // one-hot zero-fill at fill-primitive speed (~6.5 TB/s measured)
    hipMemsetAsync(out_oh, 0, (size_t)N_PTS * N_E * sizeof(float), stream);

    eprep_kernel<<<(N_E + 255) / 256, 256, 0, stream>>>(emb, ebhl, norms,
                                                        ws_head, counts);
    kargmin_kernel<<<N_PTS / 32, 128, 0, stream>>>(z, ebhl, norms, idx, counts,
                                                   out_idx, nzG, fixcnt, fixlist);
    kfix_kernel<<<1024, 256, 0, stream>>>(z, emb, norms, nzG, idx, counts,
                                          out_idx, fixcnt, fixlist);
    kzq_kernel<<<N_PTS / 64, 256, 0, stream>>>(z, emb, idx, out_zq, out_oh,
                                               loss_accum);
    kfin_kernel<<<1, 1024, 0, stream>>>(counts, loss_accum, out_loss, out_perp);
}